// Round 3
// baseline (195.730 us; speedup 1.0000x reference)
//
#include <hip/hip_runtime.h>
#include <stdint.h>

// GeometricBilinear (PGA 3,0,1) — MFMA formulation.
// R3: multi-tile pipelined blocks.
//  - Each block: T=4 tiles of 16 positions (64 pos), grid 512 blocks, 1 block/CU.
//  - ALL 78 weight fragments (79872 B) copied to LDS once per block; per-tile frag
//    reads are ds_read_b128 (~120cy, hidden) instead of per-tile L2 chains.
//  - 2 barriers per tile: P1 {prefetch mv/s/ref(t+1) -> regs; stage3(t-1); stage1(t)}
//    B_a; P2 {stage2(t); pack xs(t+1)} B_b. Barrier vmcnt(0) drains absorb all
//    global-load latency under compute.
//  - xs double-buffer; hl(t) aliases xs(t)'s buffer (dead after stage1 reads, B_a
//    between); xs(t+1) goes to the other buffer (its hl(t-1) reads end at B_a).
//  - xs c-stride 20 words (16B-aligned reads, 2-way-free writes); stage2 thread map
//    (pos=tid>>4, hc=tid&15) makes yl reads 2-way-free.
// LDS: weights [0,79872) + xs A/B [79872,121344) + yl [121344,158720).

#define NPOS_TOTAL 32768
#define T_TILES 4

#define WLDS_FRAGS 78
#define XS_SZ      20736           // 16 pos * 324 words * 4B
#define XS0_OFF    79872
#define YL_OFF     121344
#define SMEM_BYTES 158720

typedef __attribute__((ext_vector_type(8))) short short8;
typedef __attribute__((ext_vector_type(4))) float f32x4;
#define MFMA16(a,b,c) __builtin_amdgcn_mfma_f32_16x16x32_bf16((a),(b),(c),0,0,0)

// ---------------- constexpr PGA(3,0,1) blade tables (verified R1) ----------------
constexpr int BLADE_MASK[16] = {0,1,2,4,8,3,5,9,6,10,12,7,11,13,14,15};
constexpr int MASK2IDX[16]   = {0,1,2,5,3,6,8,11,4,7,9,12,10,13,14,15};

struct MulRes { int sign; int mask; };

constexpr MulRes mul_blades(int ma, int mb) {
  int lst[8] = {0,0,0,0,0,0,0,0};
  int n = 0;
  for (int g = 0; g < 4; ++g) if ((ma >> g) & 1) lst[n++] = g;
  for (int g = 0; g < 4; ++g) if ((mb >> g) & 1) lst[n++] = g;
  int sign = 1;
  bool changed = true;
  while (changed) {
    changed = false;
    int k = 0;
    while (k + 1 < n) {
      if (lst[k] > lst[k+1]) {
        int t = lst[k]; lst[k] = lst[k+1]; lst[k+1] = t;
        sign = -sign; changed = true;
      } else if (lst[k] == lst[k+1]) {
        if (lst[k] == 0) sign = 0;            // METRIC = [0,1,1,1]
        for (int m = k; m + 2 < n; ++m) lst[m] = lst[m+2];
        n -= 2; changed = true;
      } else {
        ++k;
      }
    }
  }
  int mask = 0;
  for (int m = 0; m < n; ++m) mask |= (1 << lst[m]);
  if (sign == 0) mask = 0;
  return MulRes{sign, mask};
}

struct Tables {
  float gp_sgn[16][16]; int gp_idx[16][16];
  float jn_sgn[16][16]; int jn_idx[16][16];
  constexpr Tables() : gp_sgn{}, gp_idx{}, jn_sgn{}, jn_idx{} {
    for (int j = 0; j < 16; ++j) {
      for (int k = 0; k < 16; ++k) {
        MulRes r = mul_blades(BLADE_MASK[j], BLADE_MASK[k]);
        gp_sgn[j][k] = (float)r.sign;
        gp_idx[j][k] = MASK2IDX[r.mask & 15];
        jn_sgn[j][k] = 0.0f; jn_idx[j][k] = 0;
        int mb = BLADE_MASK[j], mc = BLADE_MASK[k];
        if ((mb | mc) == 15) {
          int cb = 15 ^ mb, cc = 15 ^ mc;
          MulRes sb = mul_blades(mb, cb);
          MulRes sc = mul_blades(mc, cc);
          MulRes ro = mul_blades(cb, cc);
          int imask = ro.mask;
          int amask = 15 ^ imask;
          MulRes si = mul_blades(imask, amask);
          jn_sgn[j][k] = (float)(si.sign * ro.sign * sb.sign * sc.sign);
          jn_idx[j][k] = MASK2IDX[amask & 15];
        }
      }
    }
  }
};
constexpr Tables TBL{};

// grade of each blade, and the e0-wedge (tgt <- src, w-slot) mapping
constexpr int GRADE[16] = {0,1,1,1,1,2,2,2,2,2,2,3,3,3,3,4};
constexpr int E0_TGT[8]  = {1,5,6,7,11,12,13,15};
constexpr int E0_SRC[8]  = {0,2,3,4,8,9,10,14};
constexpr int E0_SLOT[8] = {5,6,6,6,7,7,7,8};

// ---------------- helpers (manual RNE bf16 pack — R1-verified) ----------------
__device__ __forceinline__ float bflo(unsigned u) { return __uint_as_float(u << 16); }
__device__ __forceinline__ float bfhi(unsigned u) { return __uint_as_float(u & 0xffff0000u); }
__device__ __forceinline__ unsigned pk2(float a, float b) {
  unsigned ua = __float_as_uint(a), ub = __float_as_uint(b);
  unsigned ra = (ua + 0x7fffu + ((ua >> 16) & 1u)) >> 16;   // RNE
  unsigned rb = (ub + 0x7fffu + ((ub >> 16) & 1u)) >> 16;
  return (ra & 0xffffu) | ((rb & 0xffffu) << 16);
}
__device__ __forceinline__ unsigned short bf1(float a) {
  unsigned ua = __float_as_uint(a);
  return (unsigned short)((ua + 0x7fffu + ((ua >> 16) & 1u)) >> 16);
}

// ---------------- prep: pack DISTINCT A-fragments (bf16) into ws ----------------
// 78 fragment blocks of 64 lanes x uint4 (8 bf16 in K order):
//  [0,36)   stage1 grade/e0 slots: blk = slot*4 + ot   (slot 0..8; ot 0..3 = L/R/JL/JR)
//  [36,44)  stage1 scalar: blk = 36 + h*4 + ot         (h = K-half of IN_S=64)
//  [44,62)  stage3 slots:  blk = 44 + slot*2 + ot      (ot 0..1, o = ot*16+m)
//  [62,66)  stage3 scalar: blk = 62 + h*2 + ot
//  [66,70)  stage4 wm2s:   blk = 66 + ot               (ot 0..3, o = ot*16+m, K=32)
//  [70,78)  stage4 ws2s:   blk = 70 + half*4 + ot
__global__ void gb_prep(const float* __restrict__ wlmv, const float* __restrict__ wrmv,
                        const float* __restrict__ wjlmv, const float* __restrict__ wjrmv,
                        const float* __restrict__ wls,  const float* __restrict__ wrs,
                        const float* __restrict__ wjls, const float* __restrict__ wjrs,
                        const float* __restrict__ womv, const float* __restrict__ ws2mv,
                        const float* __restrict__ wm2s, const float* __restrict__ ws2s,
                        uint4* __restrict__ wpk) {
  int t = blockIdx.x * 256 + threadIdx.x;
  if (t >= 78 * 64) return;
  int blk = t >> 6, l = t & 63;
  int m = l & 15, q = l >> 4;
  float v[8];
  if (blk < 36) {                      // stage1 mv slots
    int slot = blk >> 2, ot = blk & 3;
    const float* wmv[4] = {wlmv, wrmv, wjlmv, wjrmv};
    for (int jj = 0; jj < 8; ++jj) {
      int k = q * 8 + jj;
      v[jj] = wmv[ot][m * 288 + k * 9 + slot];
    }
  } else if (blk < 44) {               // stage1 scalar
    int b = blk - 36, h = b >> 2, ot = b & 3;
    const float* wsc[4] = {wls, wrs, wjls, wjrs};
    for (int jj = 0; jj < 8; ++jj) {
      int k = q * 8 + jj;
      v[jj] = wsc[ot][m * 64 + h * 32 + k];
    }
  } else if (blk < 62) {               // stage3 mv slots
    int b = blk - 44, slot = b >> 1, ot = b & 1;
    int o = ot * 16 + m;
    for (int jj = 0; jj < 8; ++jj) {
      int k = q * 8 + jj;
      v[jj] = womv[o * 288 + k * 9 + slot];
    }
  } else if (blk < 66) {               // stage3 scalar (ws2mv)
    int b = blk - 62, h = b >> 1, ot = b & 1;
    int o = ot * 16 + m;
    for (int jj = 0; jj < 8; ++jj) {
      int k = q * 8 + jj;
      v[jj] = ws2mv[o * 64 + h * 32 + k];
    }
  } else if (blk < 70) {               // stage4 wm2s (64x32)
    int ot = blk - 66, o = ot * 16 + m;
    for (int jj = 0; jj < 8; ++jj) {
      int k = q * 8 + jj;
      v[jj] = wm2s[o * 32 + k];
    }
  } else {                             // stage4 ws2s (64x64, two K-halves)
    int b = blk - 70, half = b >> 2, ot = b & 3;
    int o = ot * 16 + m;
    for (int jj = 0; jj < 8; ++jj) {
      int k = q * 8 + jj;
      v[jj] = ws2s[o * 64 + half * 32 + k];
    }
  }
  uint4 u;
  u.x = pk2(v[0], v[1]); u.y = pk2(v[2], v[3]);
  u.z = pk2(v[4], v[5]); u.w = pk2(v[6], v[7]);
  wpk[t] = u;
}

// ---------------- main fused kernel ----------------
__global__ __launch_bounds__(256, 1) void gb_main(
    const float* __restrict__ mv, const float* __restrict__ ref,
    const float* __restrict__ s, const uint4* __restrict__ wpk,
    float* __restrict__ out_mv, float* __restrict__ out_s) {
  __shared__ __align__(16) char smem[SMEM_BYTES];
  unsigned* ylw = (unsigned*)(smem + YL_OFF);

  const int tid  = threadIdx.x;
  const int wave = tid >> 6, lane = tid & 63;
  const int lm = lane & 15, lq = lane >> 4;
  const int i2v = lane >> 2, jg = lane & 3;
  const int P0b = blockIdx.x * (T_TILES * 16);

  // ---- weight set -> LDS (once per block; drains at first barrier) ----
  {
    const uint4* src = wpk;
    uint4* dst = (uint4*)smem;
    for (int i = tid; i < WLDS_FRAGS * 64; i += 256) dst[i] = src[i];
  }

  // frag fetch helper: fragment idx f, this lane's 16B
  auto frag = [&](int f) -> short8 {
    return *(const short8*)(smem + ((size_t)(f * 64 + lane)) * 16);
  };

  float4 mvp[8];        // mv prefetch regs for tile t+1
  float4 sp[4];         // s prefetch regs
  short8 sprev[2], scur[2];
  sprev[0] = short8{}; sprev[1] = short8{};
  scur[0] = short8{}; scur[1] = short8{};
  float rs_cur = 0.f, rs_next = 0.f;

  #pragma unroll 1
  for (int t = -1; t <= T_TILES; ++t) {
    // ================= P1 =================
    if (t + 1 < T_TILES) {
      // prefetch mv/s/ref for tile t+1 into registers
      const int P0n = P0b + (t + 1) * 16;
      const float4* mv4n = (const float4*)mv + (size_t)P0n * 128;
      #pragma unroll
      for (int kk = 0; kk < 4; ++kk) {
        int p = wave + kk * 4;
        mvp[2 * kk]     = mv4n[p * 128 + i2v * 8 + jg];
        mvp[2 * kk + 1] = mv4n[p * 128 + i2v * 8 + 4 + jg];
      }
      const float4* s4n = (const float4*)s + ((size_t)(P0n + lm)) * 16;
      sp[0] = s4n[lq * 2];     sp[1] = s4n[lq * 2 + 1];
      sp[2] = s4n[8 + lq * 2]; sp[3] = s4n[8 + lq * 2 + 1];
      rs_next = ref[((size_t)(P0n + (tid >> 4))) * 16 + 15];
    }

    if (t > 0) {
      // ---- stage 3/4 for tile t-1 (hl in buffer (t-1)&1, sfrag = sprev) ----
      const unsigned short* hb =
          (const unsigned short*)(smem + XS0_OFF + ((t - 1) & 1) * XS_SZ);
      const int P0p = P0b + (t - 1) * 16;
      if (wave < 2) {
        short8 w3g[5], w3e[4], w3s[2];
        #pragma unroll
        for (int g = 0; g < 5; ++g) w3g[g] = frag(44 + g * 2 + wave);
        #pragma unroll
        for (int m = 0; m < 4; ++m) w3e[m] = frag(44 + (5 + m) * 2 + wave);
        #pragma unroll
        for (int h = 0; h < 2; ++h) w3s[h] = frag(62 + h * 2 + wave);
        short8 bh[16];
        #pragma unroll
        for (int j = 0; j < 16; ++j)
          bh[j] = *(const short8*)&hb[lm * 520 + j * 32 + lq * 8];
        f32x4 zf = {0.f, 0.f, 0.f, 0.f};
        f32x4 a3[16];
        #pragma unroll
        for (int j = 0; j < 16; ++j) a3[j] = zf;
        #pragma unroll
        for (int j = 0; j < 16; ++j)
          a3[j] = MFMA16(w3g[GRADE[j]], bh[j], a3[j]);
        #pragma unroll
        for (int m = 0; m < 8; ++m)
          a3[E0_TGT[m]] = MFMA16(w3e[E0_SLOT[m] - 5], bh[E0_SRC[m]], a3[E0_TGT[m]]);
        #pragma unroll
        for (int h = 0; h < 2; ++h)
          a3[0] = MFMA16(w3s[h], sprev[h], a3[0]);
        float* ob = out_mv + ((size_t)(P0p + lm)) * 512 + (size_t)(wave * 16 + lq * 4) * 16;
        #pragma unroll
        for (int r = 0; r < 4; ++r) {
          #pragma unroll
          for (int g = 0; g < 4; ++g) {
            *(float4*)(ob + r * 16 + g * 4) =
                make_float4(a3[4 * g][r], a3[4 * g + 1][r], a3[4 * g + 2][r], a3[4 * g + 3][r]);
          }
        }
      } else {
        short8 bh0 = *(const short8*)&hb[lm * 520 + lq * 8];
        f32x4 zf = {0.f, 0.f, 0.f, 0.f};
        #pragma unroll
        for (int t2 = 0; t2 < 2; ++t2) {
          int otg = (wave - 2) * 2 + t2;
          f32x4 aS = zf;
          aS = MFMA16(frag(66 + otg), bh0, aS);
          aS = MFMA16(frag(70 + otg), sprev[0], aS);
          aS = MFMA16(frag(74 + otg), sprev[1], aS);
          float* osb = out_s + ((size_t)(P0p + lm)) * 64 + otg * 16 + lq * 4;
          *(float4*)osb = make_float4(aS[0], aS[1], aS[2], aS[3]);
        }
      }
    }

    if ((unsigned)t < (unsigned)T_TILES) {
      // ---- stage 1 for tile t (xs in buffer t&1, sfrag = scur) ----
      const unsigned short* xe =
          (const unsigned short*)(smem + XS0_OFF + (t & 1) * XS_SZ);
      short8 wg[5], we[4], wsc[2];
      #pragma unroll
      for (int g = 0; g < 5; ++g) wg[g] = frag(g * 4 + wave);
      #pragma unroll
      for (int m = 0; m < 4; ++m) we[m] = frag((5 + m) * 4 + wave);
      #pragma unroll
      for (int h = 0; h < 2; ++h) wsc[h] = frag(36 + h * 4 + wave);
      short8 bx[16];
      #pragma unroll
      for (int c = 0; c < 16; ++c)
        bx[c] = *(const short8*)&xe[lm * 648 + c * 40 + lq * 8];
      f32x4 zf = {0.f, 0.f, 0.f, 0.f};
      f32x4 acc[16];
      #pragma unroll
      for (int j = 0; j < 16; ++j) acc[j] = zf;
      #pragma unroll
      for (int j = 0; j < 16; ++j)
        acc[j] = MFMA16(wg[GRADE[j]], bx[j], acc[j]);
      #pragma unroll
      for (int m = 0; m < 8; ++m)
        acc[E0_TGT[m]] = MFMA16(we[E0_SLOT[m] - 5], bx[E0_SRC[m]], acc[E0_TGT[m]]);
      #pragma unroll
      for (int h = 0; h < 2; ++h)
        acc[0] = MFMA16(wsc[h], scur[h], acc[0]);
      #pragma unroll
      for (int jp = 0; jp < 8; ++jp) {
        #pragma unroll
        for (int r = 0; r < 4; ++r) {
          int o = wave * 16 + lq * 4 + r;
          ylw[o * 146 + lm * 9 + jp] = pk2(acc[2 * jp][r], acc[2 * jp + 1][r]);
        }
      }
    }
    __syncthreads();   // B_a: yl(t) ready; xs(t)/hl(t-1) reads done; prefetches landed

    // ================= P2 =================
    if ((unsigned)t < (unsigned)T_TILES) {
      // ---- stage 2: channel-local bilinear. pos = tid>>4, hc = tid&15 ----
      const int pos = tid >> 4;
      const int hc  = tid & 15;
      unsigned short* hl = (unsigned short*)(smem + XS0_OFF + (t & 1) * XS_SZ);
      float L[16], R[16], H[16];
      {
        const unsigned* pL = ylw + hc * 146 + pos * 9;
        const unsigned* pR = ylw + (16 + hc) * 146 + pos * 9;
        #pragma unroll
        for (int q = 0; q < 8; ++q) {
          unsigned a = pL[q], b = pR[q];
          L[2 * q] = bflo(a); L[2 * q + 1] = bfhi(a);
          R[2 * q] = bflo(b); R[2 * q + 1] = bfhi(b);
        }
      }
      #pragma unroll
      for (int q = 0; q < 16; ++q) H[q] = 0.f;
      #pragma unroll
      for (int j = 0; j < 16; ++j)
        #pragma unroll
        for (int k = 0; k < 16; ++k)
          if (TBL.gp_sgn[j][k] != 0.0f)
            H[TBL.gp_idx[j][k]] += TBL.gp_sgn[j][k] * L[j] * R[k];
      #pragma unroll
      for (int j = 0; j < 16; ++j)
        hl[pos * 520 + j * 32 + hc] = bf1(H[j]);
      {
        const unsigned* pJ = ylw + (32 + hc) * 146 + pos * 9;
        const unsigned* pK = ylw + (48 + hc) * 146 + pos * 9;
        #pragma unroll
        for (int q = 0; q < 8; ++q) {
          unsigned a = pJ[q];
          L[2 * q] = bflo(a) * rs_cur; L[2 * q + 1] = bfhi(a) * rs_cur;
        }
        #pragma unroll
        for (int q = 0; q < 8; ++q) {
          unsigned a = pK[q];
          R[2 * q] = bflo(a); R[2 * q + 1] = bfhi(a);
        }
      }
      #pragma unroll
      for (int q = 0; q < 16; ++q) H[q] = 0.f;
      #pragma unroll
      for (int j = 0; j < 16; ++j)
        #pragma unroll
        for (int k = 0; k < 16; ++k)
          if (TBL.jn_sgn[j][k] != 0.0f)
            H[TBL.jn_idx[j][k]] += TBL.jn_sgn[j][k] * L[j] * R[k];
      #pragma unroll
      for (int j = 0; j < 16; ++j)
        hl[pos * 520 + j * 32 + 16 + hc] = bf1(H[j]);
    }

    // rotate sfrag: sprev <- sfrag(t)
    sprev[0] = scur[0]; sprev[1] = scur[1];

    if (t + 1 < T_TILES) {
      // ---- pack xs(t+1) into buffer (t+1)&1 (hl(t-1) reads there ended at B_a) ----
      unsigned* xw = (unsigned*)(smem + XS0_OFF + ((t + 1) & 1) * XS_SZ);
      #pragma unroll
      for (int kk = 0; kk < 4; ++kk) {
        int p = wave + kk * 4;
        int base = p * 324 + jg * 80 + i2v;    // words; c-stride 20, pos-stride 324
        float4 fa = mvp[2 * kk], fb = mvp[2 * kk + 1];
        xw[base + 0 * 20] = pk2(fa.x, fb.x);
        xw[base + 1 * 20] = pk2(fa.y, fb.y);
        xw[base + 2 * 20] = pk2(fa.z, fb.z);
        xw[base + 3 * 20] = pk2(fa.w, fb.w);
      }
      // pack sfrag(t+1)
      uint4 u;
      u.x = pk2(sp[0].x, sp[0].y); u.y = pk2(sp[0].z, sp[0].w);
      u.z = pk2(sp[1].x, sp[1].y); u.w = pk2(sp[1].z, sp[1].w);
      scur[0] = __builtin_bit_cast(short8, u);
      u.x = pk2(sp[2].x, sp[2].y); u.y = pk2(sp[2].z, sp[2].w);
      u.z = pk2(sp[3].x, sp[3].y); u.w = pk2(sp[3].z, sp[3].w);
      scur[1] = __builtin_bit_cast(short8, u);
      rs_cur = rs_next;
    }
    __syncthreads();   // B_b: hl(t) + xs(t+1) ready; yl(t) reads done
  }
}

extern "C" void kernel_launch(void* const* d_in, const int* in_sizes, int n_in,
                              void* d_out, int out_size, void* d_ws, size_t ws_size,
                              hipStream_t stream) {
  (void)in_sizes; (void)n_in; (void)out_size; (void)ws_size;
  const float* mv    = (const float*)d_in[0];
  const float* ref   = (const float*)d_in[1];
  const float* s     = (const float*)d_in[2];
  // d_in[3..5] = basis/gp/jn tables: baked at compile time.
  const float* wlmv  = (const float*)d_in[6];
  const float* wls   = (const float*)d_in[7];
  const float* wrmv  = (const float*)d_in[8];
  const float* wrs   = (const float*)d_in[9];
  const float* wjlmv = (const float*)d_in[10];
  const float* wjls  = (const float*)d_in[11];
  const float* wjrmv = (const float*)d_in[12];
  const float* wjrs  = (const float*)d_in[13];
  const float* womv  = (const float*)d_in[14];
  const float* ws2mv = (const float*)d_in[15];
  const float* wm2s  = (const float*)d_in[16];
  const float* ws2s  = (const float*)d_in[17];

  float* out_mv = (float*)d_out;
  float* out_s  = out_mv + (size_t)NPOS_TOTAL * 32 * 16;
  uint4* wpk = (uint4*)d_ws;

  gb_prep<<<20, 256, 0, stream>>>(wlmv, wrmv, wjlmv, wjrmv, wls, wrs, wjls, wjrs,
                                  womv, ws2mv, wm2s, ws2s, wpk);
  gb_main<<<NPOS_TOTAL / (T_TILES * 16), 256, 0, stream>>>(mv, ref, s, wpk, out_mv, out_s);
}

// Round 4
// 188.998 us; speedup vs baseline: 1.0356x; 1.0356x over previous
//
#include <hip/hip_runtime.h>
#include <stdint.h>

// GeometricBilinear (PGA 3,0,1) — MFMA formulation.
// Per block: 16 positions, 256 threads (4 waves).
// stage1: 4 equi-linears as per-component GEMMs (M=64 stacked L/R/JL/JR, K=32, N=16 pos)
// stage2: channel-local gp/join bilinear on VALU
// stage3: output equi-linear (M=32, K=32 hidden ch) + scalar head (M=64) on MFMA.
//
// R4 = R2 (dedup'd weights from L2 + register prefetch, 84 VGPR, no spills)
//      + R1's full LDS aliasing (37376 B -> 4 blocks/CU, 4 waves/SIMD)
//      + R3's stage2 thread map (pos=tid>>4: yl reads <=2-way, free).
// Aliasing/barrier scheme (R1-verified):
//   stage0 writes xs [0,16640) -> B1 -> stage1 reads bx -> B2 -> yl writes [0,37376)
//   -> B3 -> stage2 reads L/R rows [0,32) = bytes [0,18688) -> B4 ->
//   hl writes [0,16640) (JL/JR rows [32,64) at [18688,37376) stay live) -> B5 ->
//   stage3 reads hl.

#define NPOS_TOTAL 32768

typedef __attribute__((ext_vector_type(8))) short short8;
typedef __attribute__((ext_vector_type(4))) float f32x4;
#define MFMA16(a,b,c) __builtin_amdgcn_mfma_f32_16x16x32_bf16((a),(b),(c),0,0,0)

// ---------------- constexpr PGA(3,0,1) blade tables (verified R1) ----------------
constexpr int BLADE_MASK[16] = {0,1,2,4,8,3,5,9,6,10,12,7,11,13,14,15};
constexpr int MASK2IDX[16]   = {0,1,2,5,3,6,8,11,4,7,9,12,10,13,14,15};

struct MulRes { int sign; int mask; };

constexpr MulRes mul_blades(int ma, int mb) {
  int lst[8] = {0,0,0,0,0,0,0,0};
  int n = 0;
  for (int g = 0; g < 4; ++g) if ((ma >> g) & 1) lst[n++] = g;
  for (int g = 0; g < 4; ++g) if ((mb >> g) & 1) lst[n++] = g;
  int sign = 1;
  bool changed = true;
  while (changed) {
    changed = false;
    int k = 0;
    while (k + 1 < n) {
      if (lst[k] > lst[k+1]) {
        int t = lst[k]; lst[k] = lst[k+1]; lst[k+1] = t;
        sign = -sign; changed = true;
      } else if (lst[k] == lst[k+1]) {
        if (lst[k] == 0) sign = 0;            // METRIC = [0,1,1,1]
        for (int m = k; m + 2 < n; ++m) lst[m] = lst[m+2];
        n -= 2; changed = true;
      } else {
        ++k;
      }
    }
  }
  int mask = 0;
  for (int m = 0; m < n; ++m) mask |= (1 << lst[m]);
  if (sign == 0) mask = 0;
  return MulRes{sign, mask};
}

struct Tables {
  float gp_sgn[16][16]; int gp_idx[16][16];
  float jn_sgn[16][16]; int jn_idx[16][16];
  constexpr Tables() : gp_sgn{}, gp_idx{}, jn_sgn{}, jn_idx{} {
    for (int j = 0; j < 16; ++j) {
      for (int k = 0; k < 16; ++k) {
        MulRes r = mul_blades(BLADE_MASK[j], BLADE_MASK[k]);
        gp_sgn[j][k] = (float)r.sign;
        gp_idx[j][k] = MASK2IDX[r.mask & 15];
        jn_sgn[j][k] = 0.0f; jn_idx[j][k] = 0;
        int mb = BLADE_MASK[j], mc = BLADE_MASK[k];
        if ((mb | mc) == 15) {
          int cb = 15 ^ mb, cc = 15 ^ mc;
          MulRes sb = mul_blades(mb, cb);
          MulRes sc = mul_blades(mc, cc);
          MulRes ro = mul_blades(cb, cc);
          int imask = ro.mask;
          int amask = 15 ^ imask;
          MulRes si = mul_blades(imask, amask);
          jn_sgn[j][k] = (float)(si.sign * ro.sign * sb.sign * sc.sign);
          jn_idx[j][k] = MASK2IDX[amask & 15];
        }
      }
    }
  }
};
constexpr Tables TBL{};

// grade of each blade, and the e0-wedge (tgt <- src, w-slot) mapping
constexpr int GRADE[16] = {0,1,1,1,1,2,2,2,2,2,2,3,3,3,3,4};
constexpr int E0_TGT[8]  = {1,5,6,7,11,12,13,15};
constexpr int E0_SRC[8]  = {0,2,3,4,8,9,10,14};
constexpr int E0_SLOT[8] = {5,6,6,6,7,7,7,8};

// ---------------- helpers (manual RNE bf16 pack — R1-verified) ----------------
__device__ __forceinline__ float bflo(unsigned u) { return __uint_as_float(u << 16); }
__device__ __forceinline__ float bfhi(unsigned u) { return __uint_as_float(u & 0xffff0000u); }
__device__ __forceinline__ unsigned pk2(float a, float b) {
  unsigned ua = __float_as_uint(a), ub = __float_as_uint(b);
  unsigned ra = (ua + 0x7fffu + ((ua >> 16) & 1u)) >> 16;   // RNE
  unsigned rb = (ub + 0x7fffu + ((ub >> 16) & 1u)) >> 16;
  return (ra & 0xffffu) | ((rb & 0xffffu) << 16);
}
__device__ __forceinline__ unsigned short bf1(float a) {
  unsigned ua = __float_as_uint(a);
  return (unsigned short)((ua + 0x7fffu + ((ua >> 16) & 1u)) >> 16);
}

// ---------------- prep: pack DISTINCT A-fragments (bf16) into ws ----------------
// 78 fragment blocks of 64 lanes x uint4 (8 bf16 in K order):
//  [0,36)   stage1 grade/e0 slots: blk = slot*4 + ot   (slot 0..8; ot 0..3 = L/R/JL/JR)
//  [36,44)  stage1 scalar: blk = 36 + h*4 + ot         (h = K-half of IN_S=64)
//  [44,62)  stage3 slots:  blk = 44 + slot*2 + ot      (ot 0..1, o = ot*16+m)
//  [62,66)  stage3 scalar: blk = 62 + h*2 + ot
//  [66,70)  stage4 wm2s:   blk = 66 + ot               (ot 0..3, o = ot*16+m, K=32)
//  [70,78)  stage4 ws2s:   blk = 70 + half*4 + ot
__global__ void gb_prep(const float* __restrict__ wlmv, const float* __restrict__ wrmv,
                        const float* __restrict__ wjlmv, const float* __restrict__ wjrmv,
                        const float* __restrict__ wls,  const float* __restrict__ wrs,
                        const float* __restrict__ wjls, const float* __restrict__ wjrs,
                        const float* __restrict__ womv, const float* __restrict__ ws2mv,
                        const float* __restrict__ wm2s, const float* __restrict__ ws2s,
                        uint4* __restrict__ wpk) {
  int t = blockIdx.x * 256 + threadIdx.x;
  if (t >= 78 * 64) return;
  int blk = t >> 6, l = t & 63;
  int m = l & 15, q = l >> 4;
  float v[8];
  if (blk < 36) {                      // stage1 mv slots
    int slot = blk >> 2, ot = blk & 3;
    const float* wmv[4] = {wlmv, wrmv, wjlmv, wjrmv};
    for (int jj = 0; jj < 8; ++jj) {
      int k = q * 8 + jj;
      v[jj] = wmv[ot][m * 288 + k * 9 + slot];
    }
  } else if (blk < 44) {               // stage1 scalar
    int b = blk - 36, h = b >> 2, ot = b & 3;
    const float* wsc[4] = {wls, wrs, wjls, wjrs};
    for (int jj = 0; jj < 8; ++jj) {
      int k = q * 8 + jj;
      v[jj] = wsc[ot][m * 64 + h * 32 + k];
    }
  } else if (blk < 62) {               // stage3 mv slots
    int b = blk - 44, slot = b >> 1, ot = b & 1;
    int o = ot * 16 + m;
    for (int jj = 0; jj < 8; ++jj) {
      int k = q * 8 + jj;
      v[jj] = womv[o * 288 + k * 9 + slot];
    }
  } else if (blk < 66) {               // stage3 scalar (ws2mv)
    int b = blk - 62, h = b >> 1, ot = b & 1;
    int o = ot * 16 + m;
    for (int jj = 0; jj < 8; ++jj) {
      int k = q * 8 + jj;
      v[jj] = ws2mv[o * 64 + h * 32 + k];
    }
  } else if (blk < 70) {               // stage4 wm2s (64x32)
    int ot = blk - 66, o = ot * 16 + m;
    for (int jj = 0; jj < 8; ++jj) {
      int k = q * 8 + jj;
      v[jj] = wm2s[o * 32 + k];
    }
  } else {                             // stage4 ws2s (64x64, two K-halves)
    int b = blk - 70, half = b >> 2, ot = b & 3;
    int o = ot * 16 + m;
    for (int jj = 0; jj < 8; ++jj) {
      int k = q * 8 + jj;
      v[jj] = ws2s[o * 64 + half * 32 + k];
    }
  }
  uint4 u;
  u.x = pk2(v[0], v[1]); u.y = pk2(v[2], v[3]);
  u.z = pk2(v[4], v[5]); u.w = pk2(v[6], v[7]);
  wpk[t] = u;
}

// ---------------- main fused kernel ----------------
// Single aliased LDS buffer, 37376 B (4 blocks/CU):
//  phase xs  [0,16640): halfword idx p*520 + c*32 + i          (stage0 -> stage1)
//  phase yl  [0,37376): u32 idx o*146 + pos*9 + jp             (stage1 -> stage2)
//  phase hl  [0,16640): halfword idx pos*520 + j*32 + ch       (stage2 -> stage3)
__global__ __launch_bounds__(256, 2) void gb_main(
    const float* __restrict__ mv, const float* __restrict__ ref,
    const float* __restrict__ s, const uint4* __restrict__ wpk,
    float* __restrict__ out_mv, float* __restrict__ out_s) {
  __shared__ __align__(16) char smem[37376];
  unsigned short* xs_e = (unsigned short*)smem;
  unsigned*       xs_w = (unsigned*)smem;
  unsigned short* hl_e = (unsigned short*)smem;
  unsigned*       yl_w = (unsigned*)smem;

  const int tid  = threadIdx.x;
  const int wave = tid >> 6, lane = tid & 63;
  const int lm = lane & 15, lq = lane >> 4;
  const int P0 = blockIdx.x * 16;

  // ---- stage1 weight prefetch: 5 grade frags for this wave's o-tile.
  // Issued before B1 so the barrier's vmcnt(0) drain completes them for free.
  short8 wg[5];
  #pragma unroll
  for (int g = 0; g < 5; ++g)
    wg[g] = __builtin_bit_cast(short8, wpk[(g * 4 + wave) * 64 + lane]);

  // ref scale: load early (used in stage2 with pos = tid>>4).
  const float rs = ref[((size_t)(P0 + (tid >> 4))) * 16 + 15];

  // ---- stage 0: transpose mv tile into xs (bf16) ----
  const float4* mv4 = (const float4*)mv + (size_t)P0 * 128;
  #pragma unroll
  for (int kk = 0; kk < 4; ++kk) {
    int e = tid + kk * 256;              // 0..1023 tasks
    int p = e >> 6, sub = e & 63, i2 = sub >> 2, jg = sub & 3;
    float4 fa = mv4[p * 128 + i2 * 8 + jg];
    float4 fb = mv4[p * 128 + i2 * 8 + 4 + jg];
    int base = p * 260 + jg * 4 * 16 + i2;     // u32 index: [p][c][i-pair]
    xs_w[base + 0 * 16] = pk2(fa.x, fb.x);
    xs_w[base + 1 * 16] = pk2(fa.y, fb.y);
    xs_w[base + 2 * 16] = pk2(fa.z, fb.z);
    xs_w[base + 3 * 16] = pk2(fa.w, fb.w);
  }

  // ---- s B-fragments (K=64 -> 2 frags), per lane: pos=lm, k=half*32+lq*8+jj ----
  short8 sfrag[2];
  {
    const float4* s4 = (const float4*)s + ((size_t)(P0 + lm)) * 16;
    #pragma unroll
    for (int h = 0; h < 2; ++h) {
      float4 a = s4[h * 8 + lq * 2];
      float4 b = s4[h * 8 + lq * 2 + 1];
      uint4 u;
      u.x = pk2(a.x, a.y); u.y = pk2(a.z, a.w);
      u.z = pk2(b.x, b.y); u.w = pk2(b.z, b.w);
      sfrag[h] = __builtin_bit_cast(short8, u);
    }
  }
  __syncthreads();                                           // B1: xs ready, wg in regs

  // ---- stage 1: 64-row stacked equi-linear via MFMA (this wave: o-tile = wave) ----
  {
    short8 bx[16];
    #pragma unroll
    for (int c = 0; c < 16; ++c)
      bx[c] = *(const short8*)&xs_e[lm * 520 + c * 32 + lq * 8];
    // e0 + scalar frags: issue before B2; the barrier drain completes them.
    short8 we[4];
    #pragma unroll
    for (int sidx = 0; sidx < 4; ++sidx)
      we[sidx] = __builtin_bit_cast(short8, wpk[((5 + sidx) * 4 + wave) * 64 + lane]);
    short8 wsc1[2];
    #pragma unroll
    for (int h = 0; h < 2; ++h)
      wsc1[h] = __builtin_bit_cast(short8, wpk[(36 + h * 4 + wave) * 64 + lane]);
    __syncthreads();                                         // B2: xs consumed -> yl may alias

    f32x4 zf = {0.f, 0.f, 0.f, 0.f};
    f32x4 acc[16];
    #pragma unroll
    for (int j = 0; j < 16; ++j) acc[j] = zf;
    #pragma unroll
    for (int j = 0; j < 16; ++j)
      acc[j] = MFMA16(wg[GRADE[j]], bx[j], acc[j]);
    #pragma unroll
    for (int m = 0; m < 8; ++m)
      acc[E0_TGT[m]] = MFMA16(we[E0_SLOT[m] - 5], bx[E0_SRC[m]], acc[E0_TGT[m]]);
    #pragma unroll
    for (int h = 0; h < 2; ++h)
      acc[0] = MFMA16(wsc1[h], sfrag[h], acc[0]);
    // D-frag: lane holds out[o = wave*16 + lq*4 + r][pos = lm]; pack j-pairs -> yl
    #pragma unroll
    for (int jp = 0; jp < 8; ++jp) {
      #pragma unroll
      for (int r = 0; r < 4; ++r) {
        int o = wave * 16 + lq * 4 + r;
        yl_w[o * 146 + lm * 9 + jp] = pk2(acc[2 * jp][r], acc[2 * jp + 1][r]);
      }
    }
  }
  __syncthreads();                                           // B3: yl ready

  // ---- stage 2: channel-local bilinear (VALU). thread t: pos=t>>4, hc=t&15 ----
  {
    const int pos = tid >> 4;
    const int hc  = tid & 15;
    // read L,R rows (yl rows [0,32) = bytes [0,18688)) BEFORE hl overwrites [0,16640)
    unsigned uL[8], uR[8];
    {
      const unsigned* pL = yl_w + hc * 146 + pos * 9;
      const unsigned* pR = yl_w + (16 + hc) * 146 + pos * 9;
      #pragma unroll
      for (int q = 0; q < 8; ++q) uL[q] = pL[q];
      #pragma unroll
      for (int q = 0; q < 8; ++q) uR[q] = pR[q];
    }
    __syncthreads();                                         // B4: L/R consumed -> hl may alias
    float L[16], R[16], H[16];
    #pragma unroll
    for (int q = 0; q < 8; ++q) {
      L[2*q] = bflo(uL[q]); L[2*q+1] = bfhi(uL[q]);
      R[2*q] = bflo(uR[q]); R[2*q+1] = bfhi(uR[q]);
    }
    // gp pair -> hidden channel hc
    #pragma unroll
    for (int q = 0; q < 16; ++q) H[q] = 0.f;
    #pragma unroll
    for (int j = 0; j < 16; ++j)
      #pragma unroll
      for (int k = 0; k < 16; ++k)
        if (TBL.gp_sgn[j][k] != 0.0f)
          H[TBL.gp_idx[j][k]] += TBL.gp_sgn[j][k] * L[j] * R[k];
    #pragma unroll
    for (int j = 0; j < 16; ++j)
      hl_e[pos * 520 + j * 32 + hc] = bf1(H[j]);
    // join pair -> hidden channel 16+hc (fold ref scale into L)
    // JL/JR = yl rows [32,64) = bytes [18688,37376): disjoint from hl writes.
    {
      const unsigned* pJ = yl_w + (32 + hc) * 146 + pos * 9;
      const unsigned* pK = yl_w + (48 + hc) * 146 + pos * 9;
      #pragma unroll
      for (int q = 0; q < 8; ++q) {
        unsigned a = pJ[q];
        L[2*q] = bflo(a) * rs; L[2*q+1] = bfhi(a) * rs;
      }
      #pragma unroll
      for (int q = 0; q < 8; ++q) {
        unsigned a = pK[q];
        R[2*q] = bflo(a); R[2*q+1] = bfhi(a);
      }
    }
    #pragma unroll
    for (int q = 0; q < 16; ++q) H[q] = 0.f;
    #pragma unroll
    for (int j = 0; j < 16; ++j)
      #pragma unroll
      for (int k = 0; k < 16; ++k)
        if (TBL.jn_sgn[j][k] != 0.0f)
          H[TBL.jn_idx[j][k]] += TBL.jn_sgn[j][k] * L[j] * R[k];
    #pragma unroll
    for (int j = 0; j < 16; ++j)
      hl_e[pos * 520 + j * 32 + 16 + hc] = bf1(H[j]);
  }

  // ---- stage3/4 weight prefetch: issued before B5 so the drain absorbs latency ----
  short8 w3[11];
  if (wave < 2) {
    #pragma unroll
    for (int g = 0; g < 9; ++g)
      w3[g] = __builtin_bit_cast(short8, wpk[(44 + g * 2 + wave) * 64 + lane]);
    #pragma unroll
    for (int h = 0; h < 2; ++h)
      w3[9 + h] = __builtin_bit_cast(short8, wpk[(62 + h * 2 + wave) * 64 + lane]);
  } else {
    int w2 = wave - 2;
    #pragma unroll
    for (int t2 = 0; t2 < 2; ++t2) {
      int otg = w2 * 2 + t2;
      w3[t2 * 3 + 0] = __builtin_bit_cast(short8, wpk[(66 + otg) * 64 + lane]);
      w3[t2 * 3 + 1] = __builtin_bit_cast(short8, wpk[(70 + otg) * 64 + lane]);
      w3[t2 * 3 + 2] = __builtin_bit_cast(short8, wpk[(74 + otg) * 64 + lane]);
    }
  }
  __syncthreads();                                           // B5: hl ready, w3 in regs

  // ---- stage 3 (waves 0,1): output equi-linear. stage 4 (waves 2,3): scalar head ----
  if (wave < 2) {
    short8 bh[16];
    #pragma unroll
    for (int j = 0; j < 16; ++j)
      bh[j] = *(const short8*)&hl_e[lm * 520 + j * 32 + lq * 8];
    f32x4 zf = {0.f, 0.f, 0.f, 0.f};
    f32x4 a3[16];
    #pragma unroll
    for (int j = 0; j < 16; ++j) a3[j] = zf;
    #pragma unroll
    for (int j = 0; j < 16; ++j)
      a3[j] = MFMA16(w3[GRADE[j]], bh[j], a3[j]);
    #pragma unroll
    for (int m = 0; m < 8; ++m)
      a3[E0_TGT[m]] = MFMA16(w3[E0_SLOT[m]], bh[E0_SRC[m]], a3[E0_TGT[m]]);
    #pragma unroll
    for (int h = 0; h < 2; ++h)
      a3[0] = MFMA16(w3[9 + h], sfrag[h], a3[0]);
    // store: out_mv[pos][o][j], o = wave*16 + lq*4 + r, pos = lm; vectorize over j
    float* ob = out_mv + ((size_t)(P0 + lm)) * 512 + (size_t)(wave * 16 + lq * 4) * 16;
    #pragma unroll
    for (int r = 0; r < 4; ++r) {
      #pragma unroll
      for (int g = 0; g < 4; ++g) {
        *(float4*)(ob + r * 16 + g * 4) =
            make_float4(a3[4*g][r], a3[4*g+1][r], a3[4*g+2][r], a3[4*g+3][r]);
      }
    }
  } else {
    short8 bh0 = *(const short8*)&hl_e[lm * 520 + lq * 8];
    f32x4 zf = {0.f, 0.f, 0.f, 0.f};
    #pragma unroll
    for (int t2 = 0; t2 < 2; ++t2) {
      int otg = (wave - 2) * 2 + t2;
      f32x4 aS = zf;
      aS = MFMA16(w3[t2 * 3 + 0], bh0, aS);
      aS = MFMA16(w3[t2 * 3 + 1], sfrag[0], aS);
      aS = MFMA16(w3[t2 * 3 + 2], sfrag[1], aS);
      float* osb = out_s + ((size_t)(P0 + lm)) * 64 + otg * 16 + lq * 4;
      *(float4*)osb = make_float4(aS[0], aS[1], aS[2], aS[3]);
    }
  }
}

extern "C" void kernel_launch(void* const* d_in, const int* in_sizes, int n_in,
                              void* d_out, int out_size, void* d_ws, size_t ws_size,
                              hipStream_t stream) {
  (void)in_sizes; (void)n_in; (void)out_size; (void)ws_size;
  const float* mv    = (const float*)d_in[0];
  const float* ref   = (const float*)d_in[1];
  const float* s     = (const float*)d_in[2];
  // d_in[3..5] = basis/gp/jn tables: baked at compile time.
  const float* wlmv  = (const float*)d_in[6];
  const float* wls   = (const float*)d_in[7];
  const float* wrmv  = (const float*)d_in[8];
  const float* wrs   = (const float*)d_in[9];
  const float* wjlmv = (const float*)d_in[10];
  const float* wjls  = (const float*)d_in[11];
  const float* wjrmv = (const float*)d_in[12];
  const float* wjrs  = (const float*)d_in[13];
  const float* womv  = (const float*)d_in[14];
  const float* ws2mv = (const float*)d_in[15];
  const float* wm2s  = (const float*)d_in[16];
  const float* ws2s  = (const float*)d_in[17];

  float* out_mv = (float*)d_out;
  float* out_s  = out_mv + (size_t)NPOS_TOTAL * 32 * 16;
  uint4* wpk = (uint4*)d_ws;

  gb_prep<<<20, 256, 0, stream>>>(wlmv, wrmv, wjlmv, wjrmv, wls, wrs, wjls, wjrs,
                                  womv, ws2mv, wm2s, ws2s, wpk);
  gb_main<<<NPOS_TOTAL / 16, 256, 0, stream>>>(mv, ref, s, wpk, out_mv, out_s);
}

// Round 5
// 184.661 us; speedup vs baseline: 1.0599x; 1.0235x over previous
//
#include <hip/hip_runtime.h>
#include <stdint.h>

// GeometricBilinear (PGA 3,0,1) — MFMA formulation.
// Per block: 16 positions, 256 threads (4 waves).
// stage0': LDS-resident raw mv -> transpose+bf16 pack into xs
// stage1 : 4 equi-linears as per-component GEMMs (M=64 stacked L/R/JL/JR, K=32)
// stage2 : channel-local gp/join bilinear on VALU
// stage3 : output equi-linear (M=32) + scalar head (M=64) on MFMA.
//
// R5: kill the exposed global-latency chain (R0-R4 showed occupancy 10/15/29/33%
// all give ~59-74us -> latency-chain bound, not occupancy/pipe bound).
//  - mv tile staged via __builtin_amdgcn_global_load_lds (16B DMA, no VGPRs, no
//    exposed latency; drained once at B0). Global src is chunk-swizzled
//    (low3 ^= mid3, involution) so stage0' b128 reads hit all 8 bank groups.
//  - s/ref/stage1-weights hoisted to kernel top + sched_barrier(0) pin: one
//    vmcnt queue, all complete under B0's drain. w3 pinned pre-B5 (under stage2).
//  - Barriers 6 -> 4: xs [0,16640) and yl [16640,54016) disjoint (B2 gone);
//    hl aliases xs, not yl (B4 gone).
// LDS 54016 B -> 3 blocks/CU.

#define NPOS_TOTAL 32768
#define M_OFF   16640            // raw mv region (32768 B), overlaid by yl after B1
#define SMEM_BYTES 54016

typedef __attribute__((ext_vector_type(8))) short short8;
typedef __attribute__((ext_vector_type(4))) float f32x4;
#define MFMA16(a,b,c) __builtin_amdgcn_mfma_f32_16x16x32_bf16((a),(b),(c),0,0,0)

// ---------------- constexpr PGA(3,0,1) blade tables (verified R1) ----------------
constexpr int BLADE_MASK[16] = {0,1,2,4,8,3,5,9,6,10,12,7,11,13,14,15};
constexpr int MASK2IDX[16]   = {0,1,2,5,3,6,8,11,4,7,9,12,10,13,14,15};

struct MulRes { int sign; int mask; };

constexpr MulRes mul_blades(int ma, int mb) {
  int lst[8] = {0,0,0,0,0,0,0,0};
  int n = 0;
  for (int g = 0; g < 4; ++g) if ((ma >> g) & 1) lst[n++] = g;
  for (int g = 0; g < 4; ++g) if ((mb >> g) & 1) lst[n++] = g;
  int sign = 1;
  bool changed = true;
  while (changed) {
    changed = false;
    int k = 0;
    while (k + 1 < n) {
      if (lst[k] > lst[k+1]) {
        int t = lst[k]; lst[k] = lst[k+1]; lst[k+1] = t;
        sign = -sign; changed = true;
      } else if (lst[k] == lst[k+1]) {
        if (lst[k] == 0) sign = 0;            // METRIC = [0,1,1,1]
        for (int m = k; m + 2 < n; ++m) lst[m] = lst[m+2];
        n -= 2; changed = true;
      } else {
        ++k;
      }
    }
  }
  int mask = 0;
  for (int m = 0; m < n; ++m) mask |= (1 << lst[m]);
  if (sign == 0) mask = 0;
  return MulRes{sign, mask};
}

struct Tables {
  float gp_sgn[16][16]; int gp_idx[16][16];
  float jn_sgn[16][16]; int jn_idx[16][16];
  constexpr Tables() : gp_sgn{}, gp_idx{}, jn_sgn{}, jn_idx{} {
    for (int j = 0; j < 16; ++j) {
      for (int k = 0; k < 16; ++k) {
        MulRes r = mul_blades(BLADE_MASK[j], BLADE_MASK[k]);
        gp_sgn[j][k] = (float)r.sign;
        gp_idx[j][k] = MASK2IDX[r.mask & 15];
        jn_sgn[j][k] = 0.0f; jn_idx[j][k] = 0;
        int mb = BLADE_MASK[j], mc = BLADE_MASK[k];
        if ((mb | mc) == 15) {
          int cb = 15 ^ mb, cc = 15 ^ mc;
          MulRes sb = mul_blades(mb, cb);
          MulRes sc = mul_blades(mc, cc);
          MulRes ro = mul_blades(cb, cc);
          int imask = ro.mask;
          int amask = 15 ^ imask;
          MulRes si = mul_blades(imask, amask);
          jn_sgn[j][k] = (float)(si.sign * ro.sign * sb.sign * sc.sign);
          jn_idx[j][k] = MASK2IDX[amask & 15];
        }
      }
    }
  }
};
constexpr Tables TBL{};

// grade of each blade, and the e0-wedge (tgt <- src, w-slot) mapping
constexpr int GRADE[16] = {0,1,1,1,1,2,2,2,2,2,2,3,3,3,3,4};
constexpr int E0_TGT[8]  = {1,5,6,7,11,12,13,15};
constexpr int E0_SRC[8]  = {0,2,3,4,8,9,10,14};
constexpr int E0_SLOT[8] = {5,6,6,6,7,7,7,8};

// ---------------- helpers (manual RNE bf16 pack — R1-verified) ----------------
__device__ __forceinline__ float bflo(unsigned u) { return __uint_as_float(u << 16); }
__device__ __forceinline__ float bfhi(unsigned u) { return __uint_as_float(u & 0xffff0000u); }
__device__ __forceinline__ unsigned pk2(float a, float b) {
  unsigned ua = __float_as_uint(a), ub = __float_as_uint(b);
  unsigned ra = (ua + 0x7fffu + ((ua >> 16) & 1u)) >> 16;   // RNE
  unsigned rb = (ub + 0x7fffu + ((ub >> 16) & 1u)) >> 16;
  return (ra & 0xffffu) | ((rb & 0xffffu) << 16);
}
__device__ __forceinline__ unsigned short bf1(float a) {
  unsigned ua = __float_as_uint(a);
  return (unsigned short)((ua + 0x7fffu + ((ua >> 16) & 1u)) >> 16);
}

// chunk swizzle (16B chunks): low3 ^= mid3. Involution, window(bit6+)-preserving.
__device__ __forceinline__ int cswz(int c) {
  return (c & ~7) | ((c ^ (c >> 3)) & 7);
}

// ---------------- prep: pack DISTINCT A-fragments (bf16) into ws ----------------
// 78 fragment blocks of 64 lanes x uint4 (8 bf16 in K order):
//  [0,36)   stage1 grade/e0 slots: blk = slot*4 + ot   (slot 0..8; ot 0..3 = L/R/JL/JR)
//  [36,44)  stage1 scalar: blk = 36 + h*4 + ot         (h = K-half of IN_S=64)
//  [44,62)  stage3 slots:  blk = 44 + slot*2 + ot      (ot 0..1, o = ot*16+m)
//  [62,66)  stage3 scalar: blk = 62 + h*2 + ot
//  [66,70)  stage4 wm2s:   blk = 66 + ot               (ot 0..3, o = ot*16+m, K=32)
//  [70,78)  stage4 ws2s:   blk = 70 + half*4 + ot
__global__ void gb_prep(const float* __restrict__ wlmv, const float* __restrict__ wrmv,
                        const float* __restrict__ wjlmv, const float* __restrict__ wjrmv,
                        const float* __restrict__ wls,  const float* __restrict__ wrs,
                        const float* __restrict__ wjls, const float* __restrict__ wjrs,
                        const float* __restrict__ womv, const float* __restrict__ ws2mv,
                        const float* __restrict__ wm2s, const float* __restrict__ ws2s,
                        uint4* __restrict__ wpk) {
  int t = blockIdx.x * 256 + threadIdx.x;
  if (t >= 78 * 64) return;
  int blk = t >> 6, l = t & 63;
  int m = l & 15, q = l >> 4;
  float v[8];
  if (blk < 36) {                      // stage1 mv slots
    int slot = blk >> 2, ot = blk & 3;
    const float* wmv[4] = {wlmv, wrmv, wjlmv, wjrmv};
    for (int jj = 0; jj < 8; ++jj) {
      int k = q * 8 + jj;
      v[jj] = wmv[ot][m * 288 + k * 9 + slot];
    }
  } else if (blk < 44) {               // stage1 scalar
    int b = blk - 36, h = b >> 2, ot = b & 3;
    const float* wsc[4] = {wls, wrs, wjls, wjrs};
    for (int jj = 0; jj < 8; ++jj) {
      int k = q * 8 + jj;
      v[jj] = wsc[ot][m * 64 + h * 32 + k];
    }
  } else if (blk < 62) {               // stage3 mv slots
    int b = blk - 44, slot = b >> 1, ot = b & 1;
    int o = ot * 16 + m;
    for (int jj = 0; jj < 8; ++jj) {
      int k = q * 8 + jj;
      v[jj] = womv[o * 288 + k * 9 + slot];
    }
  } else if (blk < 66) {               // stage3 scalar (ws2mv)
    int b = blk - 62, h = b >> 1, ot = b & 1;
    int o = ot * 16 + m;
    for (int jj = 0; jj < 8; ++jj) {
      int k = q * 8 + jj;
      v[jj] = ws2mv[o * 64 + h * 32 + k];
    }
  } else if (blk < 70) {               // stage4 wm2s (64x32)
    int ot = blk - 66, o = ot * 16 + m;
    for (int jj = 0; jj < 8; ++jj) {
      int k = q * 8 + jj;
      v[jj] = wm2s[o * 32 + k];
    }
  } else {                             // stage4 ws2s (64x64, two K-halves)
    int b = blk - 70, half = b >> 2, ot = b & 3;
    int o = ot * 16 + m;
    for (int jj = 0; jj < 8; ++jj) {
      int k = q * 8 + jj;
      v[jj] = ws2s[o * 64 + half * 32 + k];
    }
  }
  uint4 u;
  u.x = pk2(v[0], v[1]); u.y = pk2(v[2], v[3]);
  u.z = pk2(v[4], v[5]); u.w = pk2(v[6], v[7]);
  wpk[t] = u;
}

// ---------------- main fused kernel ----------------
// LDS 54016 B, 4 barriers:
//  xs/hl [0,16640)  halfword idx p*520 + c*32 + i    (stage0'->stage1; stage2->stage3)
//  M     [16640,49408) raw mv f32, chunk-swizzled    (DMA -> stage0')
//  yl    [16640,54016) u32 idx o*146 + pos*9 + jp    (stage1 -> stage2; overlays M)
__global__ __launch_bounds__(256, 2) void gb_main(
    const float* __restrict__ mv, const float* __restrict__ ref,
    const float* __restrict__ s, const uint4* __restrict__ wpk,
    float* __restrict__ out_mv, float* __restrict__ out_s) {
  __shared__ __align__(16) char smem[SMEM_BYTES];
  unsigned short* xs_e = (unsigned short*)smem;
  unsigned*       xs_w = (unsigned*)smem;
  unsigned short* hl_e = (unsigned short*)smem;
  unsigned*       yl_w = (unsigned*)(smem + M_OFF);

  const int tid  = threadIdx.x;
  const int wave = tid >> 6, lane = tid & 63;
  const int lm = lane & 15, lq = lane >> 4;
  const int P0 = blockIdx.x * 16;

  // ======== top prefetch cluster: every global load issued here, back-to-back ====
  // stage1 weights (11 frags, L2-hot)
  short8 wg[5], we[4], wsc1[2];
  #pragma unroll
  for (int g = 0; g < 5; ++g)
    wg[g] = __builtin_bit_cast(short8, wpk[(g * 4 + wave) * 64 + lane]);
  #pragma unroll
  for (int m = 0; m < 4; ++m)
    we[m] = __builtin_bit_cast(short8, wpk[((5 + m) * 4 + wave) * 64 + lane]);
  #pragma unroll
  for (int h = 0; h < 2; ++h)
    wsc1[h] = __builtin_bit_cast(short8, wpk[(36 + h * 4 + wave) * 64 + lane]);
  // ref scale (stage2, pos = tid>>4)
  const float rs = ref[((size_t)(P0 + (tid >> 4))) * 16 + 15];
  // s rows (packed to sfrag after B0)
  float4 sp[4];
  {
    const float4* s4 = (const float4*)s + ((size_t)(P0 + lm)) * 16;
    sp[0] = s4[lq * 2];     sp[1] = s4[lq * 2 + 1];
    sp[2] = s4[8 + lq * 2]; sp[3] = s4[8 + lq * 2 + 1];
  }
  // mv tile -> LDS raw region M via async DMA (no VGPRs, drains at B0).
  // Per wave call i: 64 lanes x 16B = 1KB window; global src chunk-swizzled so
  // stage0' transpose reads are bank-group-uniform; LDS dst linear (HW: base+lane*16).
  {
    const char* mvb = (const char*)mv + (size_t)P0 * 2048;
    const int sl = cswz(lane);
    #pragma unroll
    for (int i = 0; i < 8; ++i) {
      int window = wave * 8 + i;
      __builtin_amdgcn_global_load_lds(
          (const __attribute__((address_space(1))) unsigned int*)(mvb + (size_t)(window * 64 + sl) * 16),
          (__attribute__((address_space(3))) unsigned int*)(smem + M_OFF + window * 1024),
          16, 0, 0);
    }
  }
  __builtin_amdgcn_sched_barrier(0);     // pin: nothing sinks below this point
  __syncthreads();                       // B0: M in LDS; all top loads drained

  // ---- sfrag pack (s regs landed at B0) ----
  short8 sfrag[2];
  {
    uint4 u;
    u.x = pk2(sp[0].x, sp[0].y); u.y = pk2(sp[0].z, sp[0].w);
    u.z = pk2(sp[1].x, sp[1].y); u.w = pk2(sp[1].z, sp[1].w);
    sfrag[0] = __builtin_bit_cast(short8, u);
    u.x = pk2(sp[2].x, sp[2].y); u.y = pk2(sp[2].z, sp[2].w);
    u.z = pk2(sp[3].x, sp[3].y); u.w = pk2(sp[3].z, sp[3].w);
    sfrag[1] = __builtin_bit_cast(short8, u);
  }

  // ---- stage 0': transpose M -> xs (bf16) ----
  {
    const float4* M4 = (const float4*)(smem + M_OFF);
    const int i2 = lane >> 2, jg = lane & 3;
    #pragma unroll
    for (int kk = 0; kk < 4; ++kk) {
      int p = kk * 4 + wave;
      int cfa = p * 128 + i2 * 8 + jg;           // logical 16B-chunk index
      float4 fa = M4[cswz(cfa)];
      float4 fb = M4[cswz(cfa + 4)];
      int base = p * 260 + jg * 64 + i2;         // u32 index: [p][c][i-pair]
      xs_w[base + 0]  = pk2(fa.x, fb.x);
      xs_w[base + 16] = pk2(fa.y, fb.y);
      xs_w[base + 32] = pk2(fa.z, fb.z);
      xs_w[base + 48] = pk2(fa.w, fb.w);
    }
  }
  __syncthreads();                       // B1: xs ready; M dead -> yl may overlay

  // ---- stage 1: 64-row stacked equi-linear via MFMA (this wave: o-tile = wave) ----
  {
    short8 bx[16];
    #pragma unroll
    for (int c = 0; c < 16; ++c)
      bx[c] = *(const short8*)&xs_e[lm * 520 + c * 32 + lq * 8];
    f32x4 zf = {0.f, 0.f, 0.f, 0.f};
    f32x4 acc[16];
    #pragma unroll
    for (int j = 0; j < 16; ++j) acc[j] = zf;
    #pragma unroll
    for (int j = 0; j < 16; ++j)
      acc[j] = MFMA16(wg[GRADE[j]], bx[j], acc[j]);
    #pragma unroll
    for (int m = 0; m < 8; ++m)
      acc[E0_TGT[m]] = MFMA16(we[E0_SLOT[m] - 5], bx[E0_SRC[m]], acc[E0_TGT[m]]);
    #pragma unroll
    for (int h = 0; h < 2; ++h)
      acc[0] = MFMA16(wsc1[h], sfrag[h], acc[0]);
    // D-frag: lane holds out[o = wave*16 + lq*4 + r][pos = lm]; pack j-pairs -> yl
    #pragma unroll
    for (int jp = 0; jp < 8; ++jp) {
      #pragma unroll
      for (int r = 0; r < 4; ++r) {
        int o = wave * 16 + lq * 4 + r;
        yl_w[o * 146 + lm * 9 + jp] = pk2(acc[2 * jp][r], acc[2 * jp + 1][r]);
      }
    }
  }
  __syncthreads();                       // B3: yl ready; xs dead -> hl may overlay

  // ---- stage 2: channel-local bilinear (VALU). thread t: pos=t>>4, hc=t&15 ----
  // yl [16640,54016) and hl [0,16640) are disjoint: no mid-stage barrier needed.
  {
    const int pos = tid >> 4;
    const int hc  = tid & 15;
    float L[16], R[16], H[16];
    {
      const unsigned* pL = yl_w + hc * 146 + pos * 9;
      const unsigned* pR = yl_w + (16 + hc) * 146 + pos * 9;
      #pragma unroll
      for (int q = 0; q < 8; ++q) {
        unsigned a = pL[q], b = pR[q];
        L[2*q] = bflo(a); L[2*q+1] = bfhi(a);
        R[2*q] = bflo(b); R[2*q+1] = bfhi(b);
      }
    }
    // gp pair -> hidden channel hc
    #pragma unroll
    for (int q = 0; q < 16; ++q) H[q] = 0.f;
    #pragma unroll
    for (int j = 0; j < 16; ++j)
      #pragma unroll
      for (int k = 0; k < 16; ++k)
        if (TBL.gp_sgn[j][k] != 0.0f)
          H[TBL.gp_idx[j][k]] += TBL.gp_sgn[j][k] * L[j] * R[k];
    #pragma unroll
    for (int j = 0; j < 16; ++j)
      hl_e[pos * 520 + j * 32 + hc] = bf1(H[j]);
    // join pair -> hidden channel 16+hc (fold ref scale into L)
    {
      const unsigned* pJ = yl_w + (32 + hc) * 146 + pos * 9;
      const unsigned* pK = yl_w + (48 + hc) * 146 + pos * 9;
      #pragma unroll
      for (int q = 0; q < 8; ++q) {
        unsigned a = pJ[q];
        L[2*q] = bflo(a) * rs; L[2*q+1] = bfhi(a) * rs;
      }
      #pragma unroll
      for (int q = 0; q < 8; ++q) {
        unsigned a = pK[q];
        R[2*q] = bflo(a); R[2*q+1] = bfhi(a);
      }
    }
    #pragma unroll
    for (int q = 0; q < 16; ++q) H[q] = 0.f;
    #pragma unroll
    for (int j = 0; j < 16; ++j)
      #pragma unroll
      for (int k = 0; k < 16; ++k)
        if (TBL.jn_sgn[j][k] != 0.0f)
          H[TBL.jn_idx[j][k]] += TBL.jn_sgn[j][k] * L[j] * R[k];
    #pragma unroll
    for (int j = 0; j < 16; ++j)
      hl_e[pos * 520 + j * 32 + 16 + hc] = bf1(H[j]);
  }

  // ---- stage3/4 weight prefetch: issued under stage2's tail, drains at B5 ----
  short8 w3[11];
  if (wave < 2) {
    #pragma unroll
    for (int g = 0; g < 9; ++g)
      w3[g] = __builtin_bit_cast(short8, wpk[(44 + g * 2 + wave) * 64 + lane]);
    #pragma unroll
    for (int h = 0; h < 2; ++h)
      w3[9 + h] = __builtin_bit_cast(short8, wpk[(62 + h * 2 + wave) * 64 + lane]);
  } else {
    int w2 = wave - 2;
    #pragma unroll
    for (int t2 = 0; t2 < 2; ++t2) {
      int otg = w2 * 2 + t2;
      w3[t2 * 3 + 0] = __builtin_bit_cast(short8, wpk[(66 + otg) * 64 + lane]);
      w3[t2 * 3 + 1] = __builtin_bit_cast(short8, wpk[(70 + otg) * 64 + lane]);
      w3[t2 * 3 + 2] = __builtin_bit_cast(short8, wpk[(74 + otg) * 64 + lane]);
    }
  }
  __builtin_amdgcn_sched_barrier(0);     // pin w3 issue above the barrier
  __syncthreads();                       // B5: hl ready, w3 in regs

  // ---- stage 3 (waves 0,1): output equi-linear. stage 4 (waves 2,3): scalar head ----
  if (wave < 2) {
    short8 bh[16];
    #pragma unroll
    for (int j = 0; j < 16; ++j)
      bh[j] = *(const short8*)&hl_e[lm * 520 + j * 32 + lq * 8];
    f32x4 zf = {0.f, 0.f, 0.f, 0.f};
    f32x4 a3[16];
    #pragma unroll
    for (int j = 0; j < 16; ++j) a3[j] = zf;
    #pragma unroll
    for (int j = 0; j < 16; ++j)
      a3[j] = MFMA16(w3[GRADE[j]], bh[j], a3[j]);
    #pragma unroll
    for (int m = 0; m < 8; ++m)
      a3[E0_TGT[m]] = MFMA16(w3[E0_SLOT[m]], bh[E0_SRC[m]], a3[E0_TGT[m]]);
    #pragma unroll
    for (int h = 0; h < 2; ++h)
      a3[0] = MFMA16(w3[9 + h], sfrag[h], a3[0]);
    // store: out_mv[pos][o][j], o = wave*16 + lq*4 + r, pos = lm; vectorize over j
    float* ob = out_mv + ((size_t)(P0 + lm)) * 512 + (size_t)(wave * 16 + lq * 4) * 16;
    #pragma unroll
    for (int r = 0; r < 4; ++r) {
      #pragma unroll
      for (int g = 0; g < 4; ++g) {
        *(float4*)(ob + r * 16 + g * 4) =
            make_float4(a3[4*g][r], a3[4*g+1][r], a3[4*g+2][r], a3[4*g+3][r]);
      }
    }
  } else {
    short8 bh0 = *(const short8*)&hl_e[lm * 520 + lq * 8];
    f32x4 zf = {0.f, 0.f, 0.f, 0.f};
    #pragma unroll
    for (int t2 = 0; t2 < 2; ++t2) {
      int otg = (wave - 2) * 2 + t2;
      f32x4 aS = zf;
      aS = MFMA16(w3[t2 * 3 + 0], bh0, aS);
      aS = MFMA16(w3[t2 * 3 + 1], sfrag[0], aS);
      aS = MFMA16(w3[t2 * 3 + 2], sfrag[1], aS);
      float* osb = out_s + ((size_t)(P0 + lm)) * 64 + otg * 16 + lq * 4;
      *(float4*)osb = make_float4(aS[0], aS[1], aS[2], aS[3]);
    }
  }
}

extern "C" void kernel_launch(void* const* d_in, const int* in_sizes, int n_in,
                              void* d_out, int out_size, void* d_ws, size_t ws_size,
                              hipStream_t stream) {
  (void)in_sizes; (void)n_in; (void)out_size; (void)ws_size;
  const float* mv    = (const float*)d_in[0];
  const float* ref   = (const float*)d_in[1];
  const float* s     = (const float*)d_in[2];
  // d_in[3..5] = basis/gp/jn tables: baked at compile time.
  const float* wlmv  = (const float*)d_in[6];
  const float* wls   = (const float*)d_in[7];
  const float* wrmv  = (const float*)d_in[8];
  const float* wrs   = (const float*)d_in[9];
  const float* wjlmv = (const float*)d_in[10];
  const float* wjls  = (const float*)d_in[11];
  const float* wjrmv = (const float*)d_in[12];
  const float* wjrs  = (const float*)d_in[13];
  const float* womv  = (const float*)d_in[14];
  const float* ws2mv = (const float*)d_in[15];
  const float* wm2s  = (const float*)d_in[16];
  const float* ws2s  = (const float*)d_in[17];

  float* out_mv = (float*)d_out;
  float* out_s  = out_mv + (size_t)NPOS_TOTAL * 32 * 16;
  uint4* wpk = (uint4*)d_ws;

  gb_prep<<<20, 256, 0, stream>>>(wlmv, wrmv, wjlmv, wjrmv, wls, wrs, wjls, wjrs,
                                  womv, ws2mv, wm2s, ws2s, wpk);
  gb_main<<<NPOS_TOTAL / 16, 256, 0, stream>>>(mv, ref, s, wpk, out_mv, out_s);
}